// Round 9
// baseline (17.462 us; speedup 1.0000x reference)
//
#include <hip/hip_runtime.h>
#include <cmath>

// NCE LM loss. N = B*T rows, D = 1024, K = 20 noise ids, V = vocab.
// R9: 4 rows/block at FULL occupancy: 512 blocks x 1024 thr (16 waves)
// = 8192 waves = 32 waves/CU demand; 16KB LDS (2 blocks/CU). Each W chunk
// serves 4 rows -> W L2 traffic ~98MB -> ~47MB. Balanced wave map:
//   slot0: wave w (0..15) -> noise id w, 4 row-dots
//   waves 0..3  -> + target dot for row w        (1 row-dot)
//   waves 8..15 -> + noise 16+((w-8)>>1) vs row-pair 2*((w-8)&1) (2 row-dots)
// Per-wave terms stored directly; finalize = fixed-tree float4 sum.

#define KN 20            // noise count (fast path)

__device__ __forceinline__ float log_sigmoid_f(float x) {
    // stable log(sigmoid(x)) = min(x,0) - log1p(exp(-|x|))
    return fminf(x, 0.0f) - log1pf(expf(-fabsf(x)));
}

__device__ __forceinline__ float fma4(float4 a, float4 b, float acc) {
    acc = fmaf(a.x, b.x, acc);
    acc = fmaf(a.y, b.y, acc);
    acc = fmaf(a.z, b.z, acc);
    return fmaf(a.w, b.w, acc);
}

__device__ __forceinline__ float wave_reduce(float v) {
    #pragma unroll
    for (int off = 32; off > 0; off >>= 1) v += __shfl_xor(v, off, 64);
    return v;
}

__global__ __launch_bounds__(1024) void nce_rows4_kernel(
    const float* __restrict__ hidden,     // (N, 1024)
    const int*   __restrict__ targets,    // (N,)
    const float* __restrict__ W,          // (V, 1024)
    const int*   __restrict__ noise_ids,  // (20,)
    float* __restrict__ cbw,              // (16*nblocks,) per-wave contributions
    float inv_n, float inv_nk, float shift)
{
    __shared__ float hlds[4096];          // 16 KB: four hidden rows

    const int tid  = threadIdx.x;
    const int wave = tid >> 6;            // 0..15
    const int lane = tid & 63;
    const int r0   = blockIdx.x * 4;

    // Stage 4 hidden rows: one 16KB coalesced read, linear LDS write.
    reinterpret_cast<float4*>(hlds)[tid] =
        reinterpret_cast<const float4*>(hidden + (size_t)r0 * 1024)[tid];

    const int tgtw = targets[r0 + (wave & 3)];  // used by waves 0..3
    __syncthreads();

    // ---- slot0: noise id = wave, dotted against all 4 rows ----
    const float* wr0 = W + (size_t)noise_ids[wave] * 1024;
    float4 b0[4];
    #pragma unroll
    for (int j = 0; j < 4; ++j)
        b0[j] = *reinterpret_cast<const float4*>(wr0 + lane * 4 + j * 256);

    float a0[4] = {0.0f, 0.0f, 0.0f, 0.0f};
    #pragma unroll
    for (int r = 0; r < 4; ++r)
        #pragma unroll
        for (int j = 0; j < 4; ++j) {
            const float4 hv = *reinterpret_cast<const float4*>(
                hlds + r * 1024 + lane * 4 + j * 256);
            a0[r] = fma4(b0[j], hv, a0[r]);
        }

    // ---- slot1 ----
    float accT = 0.0f, aP0 = 0.0f, aP1 = 0.0f;
    if (wave < 4) {
        // target dot for row `wave`
        const float* wr = W + (size_t)tgtw * 1024;
        const float* hr = hlds + wave * 1024;
        #pragma unroll
        for (int j = 0; j < 4; ++j) {
            const float4 b = *reinterpret_cast<const float4*>(wr + lane * 4 + j * 256);
            const float4 a = *reinterpret_cast<const float4*>(hr + lane * 4 + j * 256);
            accT = fma4(b, a, accT);
        }
    } else if (wave >= 8) {
        // noise 16+((w-8)>>1) vs rows {rb, rb+1}, rb = 2*((w-8)&1)
        const int p  = wave - 8;
        const int n1 = 16 + (p >> 1);
        const int rb = 2 * (p & 1);
        const float* wr = W + (size_t)noise_ids[n1] * 1024;
        #pragma unroll
        for (int j = 0; j < 4; ++j) {
            const float4 b  = *reinterpret_cast<const float4*>(wr + lane * 4 + j * 256);
            const float4 h0 = *reinterpret_cast<const float4*>(
                hlds + rb * 1024 + lane * 4 + j * 256);
            const float4 h1 = *reinterpret_cast<const float4*>(
                hlds + (rb + 1) * 1024 + lane * 4 + j * 256);
            aP0 = fma4(b, h0, aP0);
            aP1 = fma4(b, h1, aP1);
        }
    }

    // ---- 7 butterflies, round-major so independent chains pipeline ----
    #pragma unroll
    for (int off = 32; off > 0; off >>= 1) {
        #pragma unroll
        for (int r = 0; r < 4; ++r) a0[r] += __shfl_xor(a0[r], off, 64);
        accT += __shfl_xor(accT, off, 64);
        aP0  += __shfl_xor(aP0,  off, 64);
        aP1  += __shfl_xor(aP1,  off, 64);
    }

    // ---- lanes 0..6 evaluate terms in parallel ----
    float v = a0[0];
    v = (lane == 1) ? a0[1] : v;
    v = (lane == 2) ? a0[2] : v;
    v = (lane == 3) ? a0[3] : v;
    v = (lane == 4) ? accT  : v;
    v = (lane == 5) ? aP0   : v;
    v = (lane == 6) ? aP1   : v;

    float term = 0.0f;
    {
        const bool is_pos = (lane == 4);
        const bool valid  = (lane < 4)
                          | (lane == 4 && wave < 4)
                          | ((lane == 5 || lane == 6) && wave >= 8);
        if (valid) {
            const float sc = v + shift;
            term = is_pos ? (-log_sigmoid_f(sc)) * inv_n
                          : (-log_sigmoid_f(-sc)) * inv_nk;
        }
    }
    term += __shfl_xor(term, 1, 64);
    term += __shfl_xor(term, 2, 64);
    term += __shfl_xor(term, 4, 64);

    if (lane == 0) cbw[blockIdx.x * 16 + wave] = term;
}

// ---- generic fallback for unexpected shapes: one block per row ----
__global__ __launch_bounds__(256) void nce_generic_kernel(
    const float* __restrict__ hidden, const int* __restrict__ targets,
    const float* __restrict__ W, const int* __restrict__ noise_ids,
    float* __restrict__ cb4, int D, int K, float inv_n, float inv_nk, float shift)
{
    const int row  = blockIdx.x;
    const int tid  = threadIdx.x;
    const int wave = tid >> 6;
    const int lane = tid & 63;

    const float* hrow = hidden + (size_t)row * D;
    const int tgt = targets[row];
    float c = 0.0f;
    for (int id = wave; id <= K; id += 4) {
        const int wrow = (id == 0) ? tgt : noise_ids[id - 1];
        const float* wv = W + (size_t)wrow * D;
        float acc = 0.0f;
        for (int k = lane; k < D; k += 64) acc = fmaf(hrow[k], wv[k], acc);
        acc = wave_reduce(acc);
        if (lane == 0) {
            const float s = acc + shift;
            c += (id == 0) ? (-log_sigmoid_f(s)) * inv_n
                           : (-log_sigmoid_f(-s)) * inv_nk;
        }
    }
    if (lane == 0) cb4[row * 4 + wave] = c;
}

// Deterministic fixed-tree sum of n4 per-wave contributions (read as float4).
__global__ __launch_bounds__(256) void nce_sum_kernel(
    const float* __restrict__ cbw, float* __restrict__ out, int n4)
{
    __shared__ float sp[4];
    const int tid  = threadIdx.x;
    const int wave = tid >> 6;
    const int lane = tid & 63;

    const float4* v = reinterpret_cast<const float4*>(cbw);
    const int nv = n4 >> 2;
    float p = 0.0f;
    for (int i = tid; i < nv; i += 256) {
        const float4 x = v[i];
        p += (x.x + x.y) + (x.z + x.w);
    }
    p = wave_reduce(p);
    if (lane == 0) sp[wave] = p;
    __syncthreads();
    if (tid == 0) out[0] = sp[0] + sp[1] + sp[2] + sp[3];
}

extern "C" void kernel_launch(void* const* d_in, const int* in_sizes, int n_in,
                              void* d_out, int out_size, void* d_ws, size_t ws_size,
                              hipStream_t stream) {
    const float* hidden    = (const float*)d_in[0];
    const int*   targets   = (const int*)d_in[1];
    const float* W         = (const float*)d_in[2];
    const int*   noise_ids = (const int*)d_in[3];

    const int N = in_sizes[1];             // B*T = 2048
    const int D = in_sizes[0] / N;         // 1024
    const int K = in_sizes[3];             // 20
    const int V = in_sizes[2] / D;         // 50257

    const float shift  = logf((float)V) - logf((float)K);
    const float inv_n  = 1.0f / (float)N;
    const float inv_nk = 1.0f / ((float)N * (float)K);

    float* cbw = (float*)d_ws;             // 4N floats, all overwritten each call

    if (D == 1024 && K == KN && (N % 4) == 0) {
        nce_rows4_kernel<<<N / 4, 1024, 0, stream>>>(
            hidden, targets, W, noise_ids, cbw, inv_n, inv_nk, shift);
    } else {
        nce_generic_kernel<<<N, 256, 0, stream>>>(
            hidden, targets, W, noise_ids, cbw, D, K, inv_n, inv_nk, shift);
    }
    nce_sum_kernel<<<1, 256, 0, stream>>>(cbw, (float*)d_out, 4 * N);
}

// Round 10
// 16.468 us; speedup vs baseline: 1.0603x; 1.0603x over previous
//
#include <hip/hip_runtime.h>
#include <cmath>

// NCE LM loss. N = B*T rows, D = 1024, K = 20 noise ids, V = vocab.
// R10 = R8 (best measured, 16.48us): 2 rows/block at FULL occupancy:
// 1024 blocks x 512 thr (8 waves) = 32 waves/CU. Both hidden rows in 8KB
// LDS; each W noise chunk serves both rows. Per-wave terms written directly
// (no closing barrier); finalize = fixed-tree float4 sum. R9's 4-row variant
// regressed (LDS read amplification + 1024-thr scheduling granularity).

#define KN 20            // noise count (fast path)

__device__ __forceinline__ float log_sigmoid_f(float x) {
    // stable log(sigmoid(x)) = min(x,0) - log1p(exp(-|x|))
    return fminf(x, 0.0f) - log1pf(expf(-fabsf(x)));
}

__device__ __forceinline__ float fma4(float4 a, float4 b, float acc) {
    acc = fmaf(a.x, b.x, acc);
    acc = fmaf(a.y, b.y, acc);
    acc = fmaf(a.z, b.z, acc);
    return fmaf(a.w, b.w, acc);
}

__device__ __forceinline__ float wave_reduce(float v) {
    #pragma unroll
    for (int off = 32; off > 0; off >>= 1) v += __shfl_xor(v, off, 64);
    return v;
}

// 2 rows per block, 8 waves. Noise id ownership: slot0 = wave, slot1 = wave+8,
// slot2 = (wave<4 ? noise 16+wave : wave<6 ? target row wave-4 : none).
__global__ __launch_bounds__(512) void nce_rows2_kernel(
    const float* __restrict__ hidden,     // (N, 1024)
    const int*   __restrict__ targets,    // (N,)
    const float* __restrict__ W,          // (V, 1024)
    const int*   __restrict__ noise_ids,  // (20,)
    float* __restrict__ cbw,              // (8*nblocks,) per-wave contributions
    float inv_n, float inv_nk, float shift)
{
    __shared__ float hlds[2048];          // 8 KB: two hidden rows

    const int tid  = threadIdx.x;
    const int wave = tid >> 6;            // 0..7
    const int lane = tid & 63;
    const int r0   = blockIdx.x * 2;

    // Stage both hidden rows: thread t loads float4 #t of 512 (one 8KB
    // coalesced read), linear LDS write.
    reinterpret_cast<float4*>(hlds)[tid] =
        reinterpret_cast<const float4*>(hidden + (size_t)r0 * 1024)[tid];

    const int tgt0 = targets[r0];
    const int tgt1 = targets[r0 + 1];
    __syncthreads();

    float acc[3][2];
    #pragma unroll
    for (int s = 0; s < 3; ++s) { acc[s][0] = 0.0f; acc[s][1] = 0.0f; }

    // Slots 0,1: noise ids wave, wave+8 — one W chunk serves both rows.
    #pragma unroll
    for (int s = 0; s < 2; ++s) {
        const int n = wave + 8 * s;
        const float* wr = W + (size_t)noise_ids[n] * 1024;
        #pragma unroll
        for (int j = 0; j < 4; ++j) {
            const float4 b  = *reinterpret_cast<const float4*>(wr + lane * 4 + j * 256);
            const float4 a0 = *reinterpret_cast<const float4*>(hlds + lane * 4 + j * 256);
            const float4 a1 = *reinterpret_cast<const float4*>(hlds + 1024 + lane * 4 + j * 256);
            acc[s][0] = fma4(b, a0, acc[s][0]);
            acc[s][1] = fma4(b, a1, acc[s][1]);
        }
    }

    // Slot 2: waves 0..3 -> noise ids 16..19 (both rows);
    //         waves 4,5 -> target dot for row wave-4; waves 6,7 idle.
    if (wave < 4) {
        const float* wr = W + (size_t)noise_ids[16 + wave] * 1024;
        #pragma unroll
        for (int j = 0; j < 4; ++j) {
            const float4 b  = *reinterpret_cast<const float4*>(wr + lane * 4 + j * 256);
            const float4 a0 = *reinterpret_cast<const float4*>(hlds + lane * 4 + j * 256);
            const float4 a1 = *reinterpret_cast<const float4*>(hlds + 1024 + lane * 4 + j * 256);
            acc[2][0] = fma4(b, a0, acc[2][0]);
            acc[2][1] = fma4(b, a1, acc[2][1]);
        }
    } else if (wave < 6) {
        const int r = wave - 4;
        const float* wr = W + (size_t)(r == 0 ? tgt0 : tgt1) * 1024;
        const float* hr = hlds + r * 1024;
        #pragma unroll
        for (int j = 0; j < 4; ++j) {
            const float4 b = *reinterpret_cast<const float4*>(wr + lane * 4 + j * 256);
            const float4 a = *reinterpret_cast<const float4*>(hr + lane * 4 + j * 256);
            acc[2][0] = fma4(b, a, acc[2][0]);
        }
    }

    // 6 butterflies, round-major so independent chains pipeline.
    #pragma unroll
    for (int off = 32; off > 0; off >>= 1)
        #pragma unroll
        for (int s = 0; s < 3; ++s) {
            acc[s][0] += __shfl_xor(acc[s][0], off, 64);
            acc[s][1] += __shfl_xor(acc[s][1], off, 64);
        }

    // Lanes 0..5 evaluate terms in parallel: lane -> (slot=lane>>1, row=lane&1).
    float v = acc[0][0];
    v = (lane == 1) ? acc[0][1] : v;
    v = (lane == 2) ? acc[1][0] : v;
    v = (lane == 3) ? acc[1][1] : v;
    v = (lane == 4) ? acc[2][0] : v;
    v = (lane == 5) ? acc[2][1] : v;

    float term = 0.0f;
    if (lane < 6) {
        const bool valid  = (lane < 4) || (wave < 4) || (lane == 4 && wave < 6);
        const bool is_pos = (lane == 4 && wave >= 4);   // target dots
        if (valid) {
            const float sc = v + shift;
            term = is_pos ? (-log_sigmoid_f(sc)) * inv_n
                          : (-log_sigmoid_f(-sc)) * inv_nk;
        }
    }
    term += __shfl_xor(term, 1, 64);
    term += __shfl_xor(term, 2, 64);
    term += __shfl_xor(term, 4, 64);

    if (lane == 0) cbw[blockIdx.x * 8 + wave] = term;
}

// ---- generic fallback for unexpected shapes: one block per row ----
__global__ __launch_bounds__(256) void nce_generic_kernel(
    const float* __restrict__ hidden, const int* __restrict__ targets,
    const float* __restrict__ W, const int* __restrict__ noise_ids,
    float* __restrict__ cb4, int D, int K, float inv_n, float inv_nk, float shift)
{
    const int row  = blockIdx.x;
    const int tid  = threadIdx.x;
    const int wave = tid >> 6;
    const int lane = tid & 63;

    const float* hrow = hidden + (size_t)row * D;
    const int tgt = targets[row];
    float c = 0.0f;
    for (int id = wave; id <= K; id += 4) {
        const int wrow = (id == 0) ? tgt : noise_ids[id - 1];
        const float* wv = W + (size_t)wrow * D;
        float acc = 0.0f;
        for (int k = lane; k < D; k += 64) acc = fmaf(hrow[k], wv[k], acc);
        acc = wave_reduce(acc);
        if (lane == 0) {
            const float s = acc + shift;
            c += (id == 0) ? (-log_sigmoid_f(s)) * inv_n
                           : (-log_sigmoid_f(-s)) * inv_nk;
        }
    }
    if (lane == 0) cb4[row * 4 + wave] = c;
}

// Deterministic fixed-tree sum of n4 per-wave contributions (read as float4).
__global__ __launch_bounds__(256) void nce_sum_kernel(
    const float* __restrict__ cbw, float* __restrict__ out, int n4)
{
    __shared__ float sp[4];
    const int tid  = threadIdx.x;
    const int wave = tid >> 6;
    const int lane = tid & 63;

    const float4* v = reinterpret_cast<const float4*>(cbw);
    const int nv = n4 >> 2;
    float p = 0.0f;
    for (int i = tid; i < nv; i += 256) {
        const float4 x = v[i];
        p += (x.x + x.y) + (x.z + x.w);
    }
    p = wave_reduce(p);
    if (lane == 0) sp[wave] = p;
    __syncthreads();
    if (tid == 0) out[0] = sp[0] + sp[1] + sp[2] + sp[3];
}

extern "C" void kernel_launch(void* const* d_in, const int* in_sizes, int n_in,
                              void* d_out, int out_size, void* d_ws, size_t ws_size,
                              hipStream_t stream) {
    const float* hidden    = (const float*)d_in[0];
    const int*   targets   = (const int*)d_in[1];
    const float* W         = (const float*)d_in[2];
    const int*   noise_ids = (const int*)d_in[3];

    const int N = in_sizes[1];             // B*T = 2048
    const int D = in_sizes[0] / N;         // 1024
    const int K = in_sizes[3];             // 20
    const int V = in_sizes[2] / D;         // 50257

    const float shift  = logf((float)V) - logf((float)K);
    const float inv_n  = 1.0f / (float)N;
    const float inv_nk = 1.0f / ((float)N * (float)K);

    float* cbw = (float*)d_ws;             // 4N floats, all overwritten each call

    if (D == 1024 && K == KN && (N % 2) == 0) {
        nce_rows2_kernel<<<N / 2, 512, 0, stream>>>(
            hidden, targets, W, noise_ids, cbw, inv_n, inv_nk, shift);
    } else {
        nce_generic_kernel<<<N, 256, 0, stream>>>(
            hidden, targets, W, noise_ids, cbw, D, K, inv_n, inv_nk, shift);
    }
    nce_sum_kernel<<<1, 256, 0, stream>>>(cbw, (float*)d_out, 4 * N);
}